// Round 6
// baseline (445.597 us; speedup 1.0000x reference)
//
#include <hip/hip_runtime.h>
#include <hip/hip_bf16.h>

typedef __hip_bfloat16 bf16;
typedef unsigned short u16;
typedef unsigned int   u32;
typedef __attribute__((ext_vector_type(8))) short short8;   // 8 bf16 = 4 VGPRs
typedef __attribute__((ext_vector_type(4))) float f32x4;
typedef __attribute__((ext_vector_type(4))) unsigned int u32x4;

#define SCALE 0.08838834764831845f  // 1/sqrt(128)
#define MFMA  __builtin_amdgcn_mfma_f32_16x16x32_bf16

__device__ __forceinline__ float u2f(u16 x) { return __uint_as_float(((u32)x) << 16); }
__device__ __forceinline__ u16   f2u(float f) {
    __hip_bfloat16 h = __float2bfloat16(f);
    return *reinterpret_cast<u16*>(&h);
}
__device__ __forceinline__ float lo16(u32 w){ return __uint_as_float(w << 16); }
__device__ __forceinline__ float hi16(u32 w){ return __uint_as_float(w & 0xffff0000u); }
__device__ __forceinline__ float rdlane(float v, int lane) {
    return __uint_as_float(__builtin_amdgcn_readlane(__float_as_uint(v), lane));
}
// XOR-swizzled index (u16 units) into a [rows][128] bf16 LDS tile.
__device__ __forceinline__ int swz(int row, int col){ return (row << 7) | (col ^ ((row & 7) << 3)); }

// ============ prep_aq: Aq = SCALE*Wq@Wk^T (frag layout, bf16) + vk = Wk@bq ====
__global__ void prep_aq(const float* __restrict__ Wq,  const float* __restrict__ Wk,
                        const float* __restrict__ bq,
                        const float* __restrict__ Wqp, const float* __restrict__ Wkp,
                        const float* __restrict__ bqp,
                        u16* __restrict__ frag, float* __restrict__ vv) {
    const int b = blockIdx.x;
    const int p = b / 33, sub = b % 33;
    const float* WA = p ? Wqp : Wq;
    const float* WB = p ? Wkp : Wk;
    const float* bA = p ? bqp : bq;
    if (sub < 32) {
        const int nt = sub >> 2, kc = sub & 3;
        u16* dst = frag + p * 16384 + sub * 512;
        for (int e = threadIdx.x; e < 512; e += 256) {
            const int lane = e >> 3, j = e & 7;
            const int k = kc * 32 + ((lane >> 4) << 3) + j;
            const int n = nt * 16 + (lane & 15);
            float a = 0.f;
            for (int cc = 0; cc < 128; cc += 4) {
                const float4 wa = *(const float4*)(WA + k * 128 + cc);
                const float4 wb = *(const float4*)(WB + n * 128 + cc);
                a += wa.x * wb.x + wa.y * wb.y + wa.z * wb.z + wa.w * wb.w;
            }
            dst[e] = f2u(a * SCALE);
        }
    } else {
        for (int d = threadIdx.x; d < 128; d += 256) {
            float a = 0.f;
            for (int cc = 0; cc < 128; cc++) a += WB[d * 128 + cc] * bA[cc];
            vv[p * 128 + d] = a;
        }
    }
}

// ============ prep_wvl: Wvl row-major bf16, bvl = 32*bv@Wl + bl ====
__global__ void prep_wvl(const float* __restrict__ Wv, const float* __restrict__ bv,
                         const float* __restrict__ Wl, const float* __restrict__ bl,
                         u16* __restrict__ wvl, float* __restrict__ bvl) {
    const int d = threadIdx.x;
    const int e = blockIdx.x;
    if (e < 128) {
        float a = 0.f;
        for (int cc = 0; cc < 128; cc++) a += Wv[e * 128 + cc] * Wl[cc * 128 + d];
        wvl[e * 128 + d] = f2u(a);
    } else {
        float a = bl[d];
        for (int cc = 0; cc < 128; cc++) a += 32.f * bv[cc] * Wl[cc * 128 + d];
        bvl[d] = a;
    }
}

// ============ Kernel A: level-1, one WAVE per (walk, side), 8KB LDS/wave ============
// R6: ALL global accesses lane-coalesced. R1-R5's per-lane row-major gather and
// per-lane wvlT rows made every load instruction touch ~64 cache lines (~3300 L1
// line-transactions/wave) -> ~200us floor independent of occupancy. Now: gather is
// wave-cooperative coalesced loads + scattered ds_write_u16 (LDS scatter is cheap);
// emb weights are row-major read 256B-coalesced; y1 broadcasts via readlane (SALU).
__global__ __launch_bounds__(256) void rwa_walk_wave(
    const float* __restrict__ timef, const float* __restrict__ ppf,
    const float* __restrict__ pnf,  const float* __restrict__ wgt,
    const int*  __restrict__ sgn,
    const u16* __restrict__ fragQ,  // [8][4][64][8] bf16 of Aq
    const float* __restrict__ vk,   // [128] = Wk@bq
    const u16* __restrict__ wvl,    // row-major [128][128] bf16 Wv@Wl
    const float* __restrict__ bvl,  // [128]
    u16* __restrict__ emb)          // bf16 [2*8192][128]
{
    __shared__ __align__(16) u16 XS[4][4096];   // 32KB total: one 8KB tile per wave
    const int t  = threadIdx.x;
    const int wv = t >> 6, l = t & 63;
    const int wid  = blockIdx.x * 4 + wv;
    const int walk = wid >> 1, side = wid & 1;
    const int c = l & 15, g = l >> 4;
    u16* const xw = &XS[wv][0];
    const int tokb = walk * 32;

    // ---- coalesced gather: whole wave loads contiguous spans, scatters to LDS ----
    {
        const float* tb = timef + (size_t)tokb * 108;
        #pragma unroll 4
        for (int rr = 0; rr < 32; rr++) {
            xw[swz(rr, 19 + l)] = f2u(tb[rr * 108 + l]);
            if (l < 44)
                xw[swz(rr, 83 + l)] = f2u(tb[rr * 108 + 64 + l]);
        }
        const size_t pbase = (size_t)tokb * 19;
        #pragma unroll
        for (int i = 0; i < 10; i++) {
            const int o = i * 64 + l;
            if (o < 608) {
                const int row = o / 19;
                const int f   = o - row * 19;
                const bool sp = (sgn[tokb + row] > 0) == (side == 0);
                const float* pb = sp ? ppf : pnf;
                xw[swz(row, f)] = f2u(pb[pbase + o]);
            }
        }
        if (l < 32) xw[swz(l, 127)] = f2u(wgt[tokb + l]);
    }

    // ---- load x A-frags (kept in regs for the whole kernel) ----
    short8 af[2][4];
    #pragma unroll
    for (int it = 0; it < 2; it++)
        #pragma unroll
        for (int kc = 0; kc < 4; kc++)
            af[it][kc] = *(const short8*)&xw[swz(it * 16 + c, kc * 32 + g * 8)];

    // ---- ra from af: ra0 = SCALE*(x[c].vk), ra1 = SCALE*(x[16+c].vk) ----
    float rr0 = 0.f, rr1 = 0.f;
    #pragma unroll
    for (int kc = 0; kc < 4; kc++) {
        const float4 ka = *(const float4*)(vk + kc * 32 + g * 8);
        const float4 kb = *(const float4*)(vk + kc * 32 + g * 8 + 4);
        const float kk[8] = {ka.x, ka.y, ka.z, ka.w, kb.x, kb.y, kb.z, kb.w};
        #pragma unroll
        for (int j = 0; j < 8; j++) {
            rr0 += u2f((u16)af[0][kc][j]) * kk[j];
            rr1 += u2f((u16)af[1][kc][j]) * kk[j];
        }
    }
    rr0 += __shfl_xor(rr0, 16); rr0 += __shfl_xor(rr0, 32);
    rr1 += __shfl_xor(rr1, 16); rr1 += __shfl_xor(rr1, 32);
    const float ra0 = rr0 * SCALE;
    const float ra1 = rr1 * SCALE;

    // ---- t = x @ Aq; t tile overwrites x tile (af reads precede in program order) ----
    #pragma unroll
    for (int nt = 0; nt < 8; nt++) {
        f32x4 a0 = {0.f, 0.f, 0.f, 0.f}, a1 = {0.f, 0.f, 0.f, 0.f};
        #pragma unroll
        for (int kc = 0; kc < 4; kc++) {
            const short8 bf = *(const short8*)(fragQ + ((nt * 4 + kc) * 64 + l) * 8);
            a0 = MFMA(af[0][kc], bf, a0, 0, 0, 0);
            a1 = MFMA(af[1][kc], bf, a1, 0, 0, 0);
        }
        #pragma unroll
        for (int r = 0; r < 4; r++) {
            xw[swz(g * 4 + r,      nt * 16 + c)] = f2u(a0[r]);
            xw[swz(16 + g * 4 + r, nt * 16 + c)] = f2u(a1[r]);
        }
    }

    // ---- S = t @ x^T (+rowadd), softmax + csum fully in registers ----
    f32x4 sa[2][2];
    #pragma unroll
    for (int it = 0; it < 2; it++) {
        short8 tg[4];
        #pragma unroll
        for (int kc = 0; kc < 4; kc++)
            tg[kc] = *(const short8*)&xw[swz(it * 16 + c, kc * 32 + g * 8)];
        #pragma unroll
        for (int jt = 0; jt < 2; jt++) {
            f32x4 acc = {0.f, 0.f, 0.f, 0.f};
            #pragma unroll
            for (int kc = 0; kc < 4; kc++)
                acc = MFMA(tg[kc], af[jt][kc], acc, 0, 0, 0);
            sa[it][jt] = acc;
        }
    }
    float cs0 = 0.f, cs1 = 0.f;
    #pragma unroll
    for (int it = 0; it < 2; it++)
    #pragma unroll
    for (int r = 0; r < 4; r++) {
        const float s0v = sa[it][0][r] + ra0;
        const float s1v = sa[it][1][r] + ra1;
        float m0 = fmaxf(s0v, s1v);
        m0 = fmaxf(m0, __shfl_xor(m0, 1));
        m0 = fmaxf(m0, __shfl_xor(m0, 2));
        m0 = fmaxf(m0, __shfl_xor(m0, 4));
        m0 = fmaxf(m0, __shfl_xor(m0, 8));
        const float p0 = __expf(s0v - m0);
        const float p1 = __expf(s1v - m0);
        float sm = p0 + p1;
        sm += __shfl_xor(sm, 1); sm += __shfl_xor(sm, 2);
        sm += __shfl_xor(sm, 4); sm += __shfl_xor(sm, 8);
        const float inv = 1.f / sm;
        cs0 += p0 * inv; cs1 += p1 * inv;
    }
    cs0 += __shfl_xor(cs0, 16); cs0 += __shfl_xor(cs0, 32);
    cs1 += __shfl_xor(cs1, 16); cs1 += __shfl_xor(cs1, 32);

    // ---- write x back from regs (t dead after tg reads) ----
    #pragma unroll
    for (int it = 0; it < 2; it++)
        #pragma unroll
        for (int kc = 0; kc < 4; kc++)
            *(short8*)&xw[swz(it * 16 + c, kc * 32 + g * 8)] = af[it][kc];

    // ---- y1 = csum^T @ x : lane owns d = (2l, 2l+1); csum broadcast via readlane ----
    float y0 = 0.f, y1v = 0.f;
    #pragma unroll
    for (int j = 0; j < 16; j++) {
        const float cj = rdlane(cs0, j);
        const u32 xv = *(const u32*)&xw[swz(j, 2 * l)];
        y0 += cj * lo16(xv); y1v += cj * hi16(xv);
    }
    #pragma unroll
    for (int j = 0; j < 16; j++) {
        const float cj = rdlane(cs1, j);
        const u32 xv = *(const u32*)&xw[swz(16 + j, 2 * l)];
        y0 += cj * lo16(xv); y1v += cj * hi16(xv);
    }

    // ---- stash y1 (f32[128]) at buffer base; broadcast-read in emb loop ----
    float* const yb = (float*)xw;
    *(float2*)&yb[2 * l] = make_float2(y0, y1v);

    // ---- emb = y1 @ Wvl + bvl : coalesced u32 weight loads, uniform LDS y reads ----
    const float2 bb = *(const float2*)&bvl[2 * l];
    float e0 = bb.x, e1 = bb.y;
    const u32* wp = (const u32*)wvl;           // [128][64] u32 view (d-pairs)
    const float4* yf = (const float4*)yb;
    #pragma unroll 8
    for (int e4 = 0; e4 < 32; e4++) {
        const float4 y4 = yf[e4];
        const u32 w0 = wp[(e4 * 4 + 0) * 64 + l];
        const u32 w1 = wp[(e4 * 4 + 1) * 64 + l];
        const u32 w2 = wp[(e4 * 4 + 2) * 64 + l];
        const u32 w3 = wp[(e4 * 4 + 3) * 64 + l];
        e0 += y4.x * lo16(w0) + y4.y * lo16(w1) + y4.z * lo16(w2) + y4.w * lo16(w3);
        e1 += y4.x * hi16(w0) + y4.y * hi16(w1) + y4.z * hi16(w2) + y4.w * hi16(w3);
    }
    const u32 pk = (u32)f2u(e0) | ((u32)f2u(e1) << 16);
    ((u32*)emb)[(side * 8192 + walk) * 64 + l] = pk;
}

// ============ Kernel B: level-2, 4-wave cooperative block per (side,b) ============
__global__ __launch_bounds__(256) void rwa_path_wave(
    const u16* __restrict__ embg, const u16* __restrict__ fragP,
    const float* __restrict__ vp, const float* __restrict__ Wvp,
    const float* __restrict__ bvp, float* __restrict__ out)
{
    __shared__ __align__(16) u16 ES[8192];     // [64][128] swizzled emb
    __shared__ __align__(16) u16 TS[8192];     // [64][128] swizzled t2
    __shared__ float raS[64];
    __shared__ float csP[4][64];
    __shared__ float y2S[4][128];
    __shared__ float y2F[128];
    __shared__ float outS[4][128];
    const int t  = threadIdx.x;
    const int sb = blockIdx.x;                 // side*128 + b
    const int wv = t >> 6, l = t & 63;
    const int c = l & 15, g = l >> 4;

    // ---- P0: load emb rows (4 threads/row) + rowadd vp-dot ----
    {
        const int row = t >> 2, q = t & 3;
        const u16* src = embg + (size_t)sb * 8192 + row * 128 + q * 32;
        const float* vq = vp + q * 32;
        float p = 0.f;
        #pragma unroll
        for (int i = 0; i < 4; i++) {
            const short8 ev = *(const short8*)(src + 8 * i);
            #pragma unroll
            for (int j = 0; j < 8; j++) p += u2f((u16)ev[j]) * vq[8 * i + j];
            *(short8*)&ES[swz(row, q * 32 + 8 * i)] = ev;
        }
        p += __shfl_xor(p, 1);
        p += __shfl_xor(p, 2);
        if (q == 0) raS[row] = p * SCALE;
    }
    __syncthreads();

    // ---- P1: t2 = emb @ Ap ; wave wv owns it-tile wv ----
    {
        const int it = wv;
        short8 afr[4];
        #pragma unroll
        for (int kc = 0; kc < 4; kc++)
            afr[kc] = *(const short8*)&ES[swz(it * 16 + c, kc * 32 + g * 8)];
        #pragma unroll
        for (int nt = 0; nt < 8; nt++) {
            f32x4 acc = {0.f, 0.f, 0.f, 0.f};
            #pragma unroll
            for (int kc = 0; kc < 4; kc++) {
                const short8 bf = *(const short8*)(fragP + ((nt * 4 + kc) * 64 + l) * 8);
                acc = MFMA(afr[kc], bf, acc, 0, 0, 0);
            }
            #pragma unroll
            for (int r = 0; r < 4; r++)
                TS[swz(it * 16 + g * 4 + r, nt * 16 + c)] = f2u(acc[r]);
        }
    }
    __syncthreads();

    // ---- P2: scores row-tile wv over all jt; softmax; csum partial ----
    {
        const int it = wv;
        short8 tg[4];
        #pragma unroll
        for (int kc = 0; kc < 4; kc++)
            tg[kc] = *(const short8*)&TS[swz(it * 16 + c, kc * 32 + g * 8)];
        f32x4 sa[4];
        float raj[4];
        #pragma unroll
        for (int jt = 0; jt < 4; jt++) {
            f32x4 acc = {0.f, 0.f, 0.f, 0.f};
            #pragma unroll
            for (int kc = 0; kc < 4; kc++) {
                const short8 be = *(const short8*)&ES[swz(jt * 16 + c, kc * 32 + g * 8)];
                acc = MFMA(tg[kc], be, acc, 0, 0, 0);
            }
            sa[jt] = acc;
            raj[jt] = raS[jt * 16 + c];
        }
        float cs[4] = {0.f, 0.f, 0.f, 0.f};
        #pragma unroll
        for (int r = 0; r < 4; r++) {
            float p0 = sa[0][r] + raj[0], p1 = sa[1][r] + raj[1];
            float p2 = sa[2][r] + raj[2], p3 = sa[3][r] + raj[3];
            float m0 = fmaxf(fmaxf(p0, p1), fmaxf(p2, p3));
            m0 = fmaxf(m0, __shfl_xor(m0, 1));
            m0 = fmaxf(m0, __shfl_xor(m0, 2));
            m0 = fmaxf(m0, __shfl_xor(m0, 4));
            m0 = fmaxf(m0, __shfl_xor(m0, 8));
            p0 = __expf(p0 - m0); p1 = __expf(p1 - m0);
            p2 = __expf(p2 - m0); p3 = __expf(p3 - m0);
            float sm = p0 + p1 + p2 + p3;
            sm += __shfl_xor(sm, 1); sm += __shfl_xor(sm, 2);
            sm += __shfl_xor(sm, 4); sm += __shfl_xor(sm, 8);
            const float inv = 1.f / sm;
            cs[0] += p0 * inv; cs[1] += p1 * inv; cs[2] += p2 * inv; cs[3] += p3 * inv;
        }
        #pragma unroll
        for (int jt = 0; jt < 4; jt++) {
            cs[jt] += __shfl_xor(cs[jt], 16);
            cs[jt] += __shfl_xor(cs[jt], 32);
        }
        if (g == 0) {
            #pragma unroll
            for (int jt = 0; jt < 4; jt++) csP[wv][jt * 16 + c] = cs[jt];
        }
    }
    __syncthreads();

    // ---- P3: y2 partial; wave wv handles j = wv*16..+15 ; lane owns d=2l,2l+1 ----
    {
        float y0 = 0.f, y1v = 0.f;
        #pragma unroll
        for (int jj = 0; jj < 16; jj++) {
            const int j = wv * 16 + jj;
            const float cj = csP[0][j] + csP[1][j] + csP[2][j] + csP[3][j];
            const u32 xv = *(const u32*)&ES[swz(j, 2 * l)];
            y0 += cj * lo16(xv); y1v += cj * hi16(xv);
        }
        y2S[wv][2 * l] = y0; y2S[wv][2 * l + 1] = y1v;
    }
    __syncthreads();
    if (t < 128) y2F[t] = y2S[0][t] + y2S[1][t] + y2S[2][t] + y2S[3][t];
    __syncthreads();

    // ---- P4: out partial; wave wv handles e = wv*32..+31 (Wvp f32, coalesced) ----
    {
        float o0 = 0.f, o1 = 0.f;
        const float2* w2p = (const float2*)Wvp;
        #pragma unroll
        for (int k = 0; k < 32; k++) {
            const int e = wv * 32 + k;
            const float ye = y2F[e];
            const float2 w2 = w2p[e * 64 + l];
            o0 += ye * w2.x; o1 += ye * w2.y;
        }
        outS[wv][2 * l] = o0; outS[wv][2 * l + 1] = o1;
    }
    __syncthreads();
    if (t < 128)
        out[sb * 128 + t] = 64.f * bvp[t] + outS[0][t] + outS[1][t] + outS[2][t] + outS[3][t];
}

// ============ Fallback: R3's proven fused kernel (used only if ws too small) ============
__global__ __launch_bounds__(256) void rwa_fused_fb(
    const float* timef, const float* ppf, const float* pnf, const float* wgt,
    const int* __restrict__ sgn,
    const float* Wq, const float* bq, const float* Wk, const float* bk,
    const float* Wv, const float* bv, const float* Wl, const float* bl,
    const float* Wqp, const float* bqp, const float* Wkp, const float* bkp,
    const float* Wvp, const float* bvp, float* out)
{
    extern __shared__ __align__(16) char S[];
    char* const U = S;
    float (* const sc)[33]     = (float(*)[33])(S + 41088);
    u16   (* const embs)[128]  = (u16  (*)[128])(S + 45312);
    float* const csumA         = (float*)(S + 61696);
    float* const y1            = (float*)(S + 61824);
    float* const e1            = (float*)(S + 62336);
    u16   (* const xs)[128]   = (u16  (*)[128])U;
    float (* const qs)[128]   = (float(*)[128])(U + 8192);
    float (* const ks)[129]   = (float(*)[129])(U + 8192 + 16384);
    float (* const k2s)[129]  = (float(*)[129])U;
    float (* const qrow)[128] = (float(*)[128])(U + 33024);
    float (* const csum2)[64] = (float(*)[64])(U + 35072);

    const int t    = threadIdx.x;
    const int side = blockIdx.x >> 7;
    const int b    = blockIdx.x & 127;
    const int wv_  = t >> 6;
    const int lane = t & 63;

    for (int w = 0; w < 64; ++w) {
        const int tokb = (b * 64 + w) * 32;
        for (int o = t; o < 32 * 128; o += 256) {
            const int l = o >> 7, f = o & 127;
            const int tok = tokb + l;
            float v;
            if (f < 19) {
                const bool takeP = (sgn[tok] > 0) == (side == 0);
                v = takeP ? ppf[tok * 19 + f] : pnf[tok * 19 + f];
            } else if (f < 127) v = timef[tok * 108 + (f - 19)];
            else v = wgt[tok];
            xs[l][f] = f2u(v);
        }
        __syncthreads();
        {
            const int d = t & 127, l0 = t >> 7;
            float aq[16], ak[16];
            const float bqv = bq[d], bkv = bk[d];
            #pragma unroll
            for (int i = 0; i < 16; i++) { aq[i] = bqv; ak[i] = bkv; }
            for (int e = 0; e < 128; e += 4) {
                float xv[16][4];
                #pragma unroll
                for (int i = 0; i < 16; i++) {
                    const ushort4 u = *(const ushort4*)&xs[l0 + 2 * i][e];
                    xv[i][0] = u2f(u.x); xv[i][1] = u2f(u.y);
                    xv[i][2] = u2f(u.z); xv[i][3] = u2f(u.w);
                }
                #pragma unroll
                for (int r = 0; r < 4; r++) {
                    const float wq = Wq[(e + r) * 128 + d];
                    const float wk = Wk[(e + r) * 128 + d];
                    #pragma unroll
                    for (int i = 0; i < 16; i++) {
                        aq[i] += xv[i][r] * wq; ak[i] += xv[i][r] * wk;
                    }
                }
            }
            #pragma unroll
            for (int i = 0; i < 16; i++) { const int l = l0 + 2 * i; qs[l][d] = aq[i]; ks[l][d] = ak[i]; }
        }
        __syncthreads();
        for (int o = t; o < 1024; o += 256) {
            const int i = o >> 5, j = o & 31;
            float a0 = 0, a1 = 0, a2 = 0, a3 = 0;
            for (int e = 0; e < 128; e += 4) {
                const float4 q4 = *(const float4*)&qs[i][e];
                a0 += q4.x * ks[j][e];     a1 += q4.y * ks[j][e + 1];
                a2 += q4.z * ks[j][e + 2]; a3 += q4.w * ks[j][e + 3];
            }
            sc[i][j] = (a0 + a1 + a2 + a3) * SCALE;
        }
        __syncthreads();
        if (t < 32) {
            float m = -1e30f;
            for (int j = 0; j < 32; j++) m = fmaxf(m, sc[t][j]);
            float s = 0.f;
            for (int j = 0; j < 32; j++) { const float e0 = __expf(sc[t][j] - m); sc[t][j] = e0; s += e0; }
            const float inv = 1.f / s;
            for (int j = 0; j < 32; j++) sc[t][j] *= inv;
        }
        __syncthreads();
        if (t < 32) { float s = 0.f; for (int i = 0; i < 32; i++) s += sc[i][t]; csumA[t] = s; }
        __syncthreads();
        if (t < 128) { float a = 0.f; for (int j = 0; j < 32; j++) a += csumA[j] * u2f(xs[j][t]); y1[t] = a; }
        __syncthreads();
        if (t < 128) {
            float a = 32.f * bv[t];
            for (int e = 0; e < 128; e++) a += y1[e] * Wv[e * 128 + t];
            e1[t] = a;
        }
        __syncthreads();
        if (t < 128) {
            float a = bl[t];
            for (int f = 0; f < 128; f++) a += e1[f] * Wl[f * 128 + t];
            embs[w][t] = f2u(a);
        }
        __syncthreads();
    }
    {
        const int d = t & 127, j0 = t >> 7;
        float ak2[32];
        const float bkv = bkp[d];
        #pragma unroll
        for (int i = 0; i < 32; i++) ak2[i] = bkv;
        for (int e = 0; e < 128; e++) {
            const float wk = Wkp[e * 128 + d];
            #pragma unroll
            for (int i = 0; i < 32; i++) ak2[i] += u2f(embs[j0 + 2 * i][e]) * wk;
        }
        #pragma unroll
        for (int i = 0; i < 32; i++) k2s[j0 + 2 * i][d] = ak2[i];
    }
    csum2[wv_][lane] = 0.f;
    __syncthreads();
    for (int i0 = 0; i0 < 64; i0 += 4) {
        const int r = i0 + wv_;
        {
            float a0 = bqp[lane], a1 = bqp[lane + 64];
            for (int e = 0; e < 128; e++) {
                const float xv = u2f(embs[r][e]);
                a0 += xv * Wqp[e * 128 + lane];
                a1 += xv * Wqp[e * 128 + lane + 64];
            }
            qrow[wv_][lane] = a0; qrow[wv_][lane + 64] = a1;
        }
        {
            const int j = lane;
            float s = 0.f;
            for (int e = 0; e < 128; e += 4) {
                const float4 q4 = *(const float4*)&qrow[wv_][e];
                s += q4.x * k2s[j][e] + q4.y * k2s[j][e + 1] + q4.z * k2s[j][e + 2] + q4.w * k2s[j][e + 3];
            }
            s *= SCALE;
            float m = s;
            #pragma unroll
            for (int off = 32; off; off >>= 1) m = fmaxf(m, __shfl_xor(m, off));
            const float e0 = __expf(s - m);
            float sum = e0;
            #pragma unroll
            for (int off = 32; off; off >>= 1) sum += __shfl_xor(sum, off);
            csum2[wv_][j] += e0 / sum;
        }
        __syncthreads();
    }
    if (t < 64) csum2[0][t] = csum2[0][t] + csum2[1][t] + csum2[2][t] + csum2[3][t];
    __syncthreads();
    if (t < 128) { float a = 0.f; for (int j = 0; j < 64; j++) a += csum2[0][j] * u2f(embs[j][t]); y1[t] = a; }
    __syncthreads();
    if (t < 128) {
        float a = 64.f * bvp[t];
        for (int e = 0; e < 128; e++) a += y1[e] * Wvp[e * 128 + t];
        out[blockIdx.x * 128 + t] = a;
    }
}

extern "C" void kernel_launch(void* const* d_in, const int* in_sizes, int n_in,
                              void* d_out, int out_size, void* d_ws, size_t ws_size,
                              hipStream_t stream) {
    const float* timef = (const float*)d_in[0];
    const float* ppf   = (const float*)d_in[1];
    const float* pnf   = (const float*)d_in[2];
    const float* wgt   = (const float*)d_in[3];
    const int*   sgn   = (const int*)  d_in[4];
    const float* Wq  = (const float*)d_in[5];  const float* bq  = (const float*)d_in[6];
    const float* Wk  = (const float*)d_in[7];  const float* bk  = (const float*)d_in[8];
    const float* Wv  = (const float*)d_in[9];  const float* bv  = (const float*)d_in[10];
    const float* Wl  = (const float*)d_in[11]; const float* bl  = (const float*)d_in[12];
    const float* Wqp = (const float*)d_in[13]; const float* bqp = (const float*)d_in[14];
    const float* Wkp = (const float*)d_in[15]; const float* bkp = (const float*)d_in[16];
    const float* Wvp = (const float*)d_in[17]; const float* bvp = (const float*)d_in[18];
    float* out = (float*)d_out;
    (void)in_sizes; (void)n_in; (void)out_size;

    // ws: fragQ+fragP 64KB | vk/vp 1KB | wvl 32KB | bvl 512B | emb 4MB
    const size_t need = 99840 + (size_t)2 * 8192 * 128 * sizeof(u16);
    if (ws_size >= need) {
        u16*   frag = (u16*)d_ws;                          // slots 0 (Aq), 1 (Ap)
        float* vv   = (float*)((char*)d_ws + 65536);       // vk | vp
        u16*   wvl  = (u16*)((char*)d_ws + 66560);
        float* bvl  = (float*)((char*)d_ws + 99328);
        u16*   emb  = (u16*)((char*)d_ws + 99840);
        hipLaunchKernelGGL(prep_aq,  dim3(66),  dim3(256), 0, stream,
                           Wq, Wk, bq, Wqp, Wkp, bqp, frag, vv);
        hipLaunchKernelGGL(prep_wvl, dim3(129), dim3(128), 0, stream, Wv, bv, Wl, bl, wvl, bvl);
        hipLaunchKernelGGL(rwa_walk_wave, dim3(4096), dim3(256), 0, stream,
                           timef, ppf, pnf, wgt, sgn, frag, vv, wvl, bvl, emb);
        hipLaunchKernelGGL(rwa_path_wave, dim3(256), dim3(256), 0, stream,
                           emb, frag + 16384, vv + 128, Wvp, bvp, out);
    } else {
        hipLaunchKernelGGL(rwa_fused_fb, dim3(256), dim3(256), 62848, stream,
                           timef, ppf, pnf, wgt, sgn, Wq, bq, Wk, bk, Wv, bv, Wl, bl,
                           Wqp, bqp, Wkp, bkp, Wvp, bvp, out);
    }
}

// Round 7
// 345.086 us; speedup vs baseline: 1.2913x; 1.2913x over previous
//
#include <hip/hip_runtime.h>
#include <hip/hip_bf16.h>

typedef __hip_bfloat16 bf16;
typedef unsigned short u16;
typedef unsigned int   u32;
typedef __attribute__((ext_vector_type(8))) short short8;   // 8 bf16 = 4 VGPRs
typedef __attribute__((ext_vector_type(4))) float f32x4;
typedef __attribute__((ext_vector_type(4))) unsigned int u32x4;

#define SCALE 0.08838834764831845f  // 1/sqrt(128)
#define MFMA  __builtin_amdgcn_mfma_f32_16x16x32_bf16

__device__ __forceinline__ float u2f(u16 x) { return __uint_as_float(((u32)x) << 16); }
__device__ __forceinline__ u16   f2u(float f) {
    __hip_bfloat16 h = __float2bfloat16(f);
    return *reinterpret_cast<u16*>(&h);
}
__device__ __forceinline__ float lo16(u32 w){ return __uint_as_float(w << 16); }
__device__ __forceinline__ float hi16(u32 w){ return __uint_as_float(w & 0xffff0000u); }
__device__ __forceinline__ float rdlane(float v, int lane) {
    return __uint_as_float(__builtin_amdgcn_readlane(__float_as_uint(v), lane));
}
// XOR-swizzled index (u16 units) into a [rows][128] bf16 LDS tile.
__device__ __forceinline__ int swz(int row, int col){ return (row << 7) | (col ^ ((row & 7) << 3)); }

// ============ prep_aq: Aq = SCALE*Wq@Wk^T (frag layout, bf16) + vk = Wk@bq ====
__global__ void prep_aq(const float* __restrict__ Wq,  const float* __restrict__ Wk,
                        const float* __restrict__ bq,
                        const float* __restrict__ Wqp, const float* __restrict__ Wkp,
                        const float* __restrict__ bqp,
                        u16* __restrict__ frag, float* __restrict__ vv) {
    const int b = blockIdx.x;
    const int p = b / 33, sub = b % 33;
    const float* WA = p ? Wqp : Wq;
    const float* WB = p ? Wkp : Wk;
    const float* bA = p ? bqp : bq;
    if (sub < 32) {
        const int nt = sub >> 2, kc = sub & 3;
        u16* dst = frag + p * 16384 + sub * 512;
        for (int e = threadIdx.x; e < 512; e += 256) {
            const int lane = e >> 3, j = e & 7;
            const int k = kc * 32 + ((lane >> 4) << 3) + j;
            const int n = nt * 16 + (lane & 15);
            float a = 0.f;
            for (int cc = 0; cc < 128; cc += 4) {
                const float4 wa = *(const float4*)(WA + k * 128 + cc);
                const float4 wb = *(const float4*)(WB + n * 128 + cc);
                a += wa.x * wb.x + wa.y * wb.y + wa.z * wb.z + wa.w * wb.w;
            }
            dst[e] = f2u(a * SCALE);
        }
    } else {
        for (int d = threadIdx.x; d < 128; d += 256) {
            float a = 0.f;
            for (int cc = 0; cc < 128; cc++) a += WB[d * 128 + cc] * bA[cc];
            vv[p * 128 + d] = a;
        }
    }
}

// ============ prep_wvl: Wvl in pair-major (mid path) AND frag layout (big path) ====
// wvlT u32 view: wvlT32[(d>>1)*128 + e] = pack(Wvl[e][d&~1], Wvl[e][d|1])
// wvlF frag: wvlF[((d>>4)*4 + (e>>5))*512 + (((e>>3)&3)*16 + (d&15))*8 + (e&7)]
__global__ void prep_wvl(const float* __restrict__ Wv, const float* __restrict__ bv,
                         const float* __restrict__ Wl, const float* __restrict__ bl,
                         u16* __restrict__ wvlT, u16* __restrict__ wvlF,
                         float* __restrict__ bvl) {
    const int d = threadIdx.x;
    const int e = blockIdx.x;
    if (e < 128) {
        float a = 0.f;
        for (int cc = 0; cc < 128; cc++) a += Wv[e * 128 + cc] * Wl[cc * 128 + d];
        const u16 u = f2u(a);
        wvlT[(d >> 1) * 256 + e * 2 + (d & 1)] = u;
        wvlF[(((d >> 4) * 4) + (e >> 5)) * 512 + (((e >> 3) & 3) * 16 + (d & 15)) * 8 + (e & 7)] = u;
    } else {
        float a = bl[d];
        for (int cc = 0; cc < 128; cc++) a += 32.f * bv[cc] * Wl[cc * 128 + d];
        bvl[d] = a;
    }
}

// ============ Kernel A (big-ws): level-1 attention ending at y1 (f32) ============
// R7: emb GEMV tail (≈800 instr/wave, the largest block) moved out to an MFMA GEMM.
// Wave-private 8KB LDS tile, no barriers, R5-proven gather/softmax body.
__global__ __launch_bounds__(256) void rwa_walk_y1(
    const float* __restrict__ timef, const float* __restrict__ ppf,
    const float* __restrict__ pnf,  const float* __restrict__ wgt,
    const int*  __restrict__ sgn,
    const u16* __restrict__ fragQ,  // [8][4][64][8] bf16 of Aq
    const float* __restrict__ vk,   // [128] = Wk@bq
    float* __restrict__ y1g)        // f32 [16384][128]
{
    __shared__ __align__(16) u16 XS[4][4096];   // 32KB total: one 8KB tile per wave
    const int t  = threadIdx.x;
    const int wv = t >> 6, l = t & 63;
    const int wid  = blockIdx.x * 4 + wv;
    const int walk = wid >> 1, side = wid & 1;
    const int c = l & 15, g = l >> 4;
    u16* const xw = &XS[wv][0];

    // ---- gather (R5-proven chunked, low reg pressure) ----
    const int row = l & 31, h = l >> 5;
    const int tok = walk * 32 + row;
    const float* tfp = timef + tok * 108;
    const float* pb = ((sgn[tok] > 0) == (side == 0)) ? (ppf + tok * 19) : (pnf + tok * 19);
    float ra = 0.f;
    #pragma unroll
    for (int ch = 0; ch < 8; ch++) {
        float tmp[8];
        #pragma unroll
        for (int j = 0; j < 8; j++) {
            const int hf = ch * 8 + j;
            float val;
            if (h == 0) {
                val = (hf < 19) ? pb[hf] : tfp[hf - 19];
            } else {
                val = (hf < 63) ? tfp[45 + hf] : wgt[tok];
            }
            tmp[j] = val;
        }
        const float4 k4a = *(const float4*)(vk + h * 64 + ch * 8);
        const float4 k4b = *(const float4*)(vk + h * 64 + ch * 8 + 4);
        ra += tmp[0] * k4a.x + tmp[1] * k4a.y + tmp[2] * k4a.z + tmp[3] * k4a.w
            + tmp[4] * k4b.x + tmp[5] * k4b.y + tmp[6] * k4b.z + tmp[7] * k4b.w;
        short8 pk;
        #pragma unroll
        for (int j = 0; j < 8; j++) pk[j] = (short)f2u(tmp[j]);
        *(short8*)&xw[swz(row, h * 64 + ch * 8)] = pk;
    }
    ra += __shfl_xor(ra, 32);
    ra *= SCALE;

    // ---- load x A-frags (kept in regs for the whole kernel) ----
    short8 af[2][4];
    #pragma unroll
    for (int it = 0; it < 2; it++)
        #pragma unroll
        for (int kc = 0; kc < 4; kc++)
            af[it][kc] = *(const short8*)&xw[swz(it * 16 + c, kc * 32 + g * 8)];

    // ---- t = x @ Aq; t tile overwrites x tile ----
    #pragma unroll
    for (int nt = 0; nt < 8; nt++) {
        f32x4 a0 = {0.f, 0.f, 0.f, 0.f}, a1 = {0.f, 0.f, 0.f, 0.f};
        #pragma unroll
        for (int kc = 0; kc < 4; kc++) {
            const short8 bf = *(const short8*)(fragQ + ((nt * 4 + kc) * 64 + l) * 8);
            a0 = MFMA(af[0][kc], bf, a0, 0, 0, 0);
            a1 = MFMA(af[1][kc], bf, a1, 0, 0, 0);
        }
        #pragma unroll
        for (int r = 0; r < 4; r++) {
            xw[swz(g * 4 + r,      nt * 16 + c)] = f2u(a0[r]);
            xw[swz(16 + g * 4 + r, nt * 16 + c)] = f2u(a1[r]);
        }
    }

    // ---- S = t @ x^T (+rowadd), softmax + csum fully in registers ----
    f32x4 sa[2][2];
    #pragma unroll
    for (int it = 0; it < 2; it++) {
        short8 tg[4];
        #pragma unroll
        for (int kc = 0; kc < 4; kc++)
            tg[kc] = *(const short8*)&xw[swz(it * 16 + c, kc * 32 + g * 8)];
        #pragma unroll
        for (int jt = 0; jt < 2; jt++) {
            f32x4 acc = {0.f, 0.f, 0.f, 0.f};
            #pragma unroll
            for (int kc = 0; kc < 4; kc++)
                acc = MFMA(tg[kc], af[jt][kc], acc, 0, 0, 0);
            sa[it][jt] = acc;
        }
    }
    const float ra0 = __shfl(ra, c);
    const float ra1 = __shfl(ra, 16 + c);
    float cs0 = 0.f, cs1 = 0.f;
    #pragma unroll
    for (int it = 0; it < 2; it++)
    #pragma unroll
    for (int r = 0; r < 4; r++) {
        const float s0v = sa[it][0][r] + ra0;
        const float s1v = sa[it][1][r] + ra1;
        float m0 = fmaxf(s0v, s1v);
        m0 = fmaxf(m0, __shfl_xor(m0, 1));
        m0 = fmaxf(m0, __shfl_xor(m0, 2));
        m0 = fmaxf(m0, __shfl_xor(m0, 4));
        m0 = fmaxf(m0, __shfl_xor(m0, 8));
        const float p0 = __expf(s0v - m0);
        const float p1 = __expf(s1v - m0);
        float sm = p0 + p1;
        sm += __shfl_xor(sm, 1); sm += __shfl_xor(sm, 2);
        sm += __shfl_xor(sm, 4); sm += __shfl_xor(sm, 8);
        const float inv = 1.f / sm;
        cs0 += p0 * inv; cs1 += p1 * inv;
    }
    cs0 += __shfl_xor(cs0, 16); cs0 += __shfl_xor(cs0, 32);
    cs1 += __shfl_xor(cs1, 16); cs1 += __shfl_xor(cs1, 32);

    // ---- write x back from regs (t dead after tg reads) ----
    #pragma unroll
    for (int it = 0; it < 2; it++)
        #pragma unroll
        for (int kc = 0; kc < 4; kc++)
            *(short8*)&xw[swz(it * 16 + c, kc * 32 + g * 8)] = af[it][kc];

    // ---- y1 = csum^T @ x : lane owns d = (2l, 2l+1); csum broadcast via readlane ----
    float y0 = 0.f, y1v = 0.f;
    #pragma unroll
    for (int j = 0; j < 16; j++) {
        const float cj = rdlane(cs0, j);
        const u32 xv = *(const u32*)&xw[swz(j, 2 * l)];
        y0 += cj * lo16(xv); y1v += cj * hi16(xv);
    }
    #pragma unroll
    for (int j = 0; j < 16; j++) {
        const float cj = rdlane(cs1, j);
        const u32 xv = *(const u32*)&xw[swz(16 + j, 2 * l)];
        y0 += cj * lo16(xv); y1v += cj * hi16(xv);
    }

    // ---- store y1 f32 (coalesced 512B/wave); emb handled by MFMA GEMM kernel ----
    *(float2*)&y1g[((size_t)(side * 8192 + walk)) * 128 + 2 * l] = make_float2(y0, y1v);
}

// ============ emb GEMM: emb = y1 @ Wvl + bvl (hi/lo bf16 split, f32-grade) ============
// grid 256 x 256 thr: block owns 64 rows; wave owns 16 rows; 64 MFMA/wave.
__global__ __launch_bounds__(256) void rwa_emb_gemm(
    const float* __restrict__ y1g, const u16* __restrict__ wvlF,
    const float* __restrict__ bvl, u16* __restrict__ emb)
{
    __shared__ __align__(16) u16 AH[8192];   // hi bf16, swz [64][128]
    __shared__ __align__(16) u16 AL[8192];   // lo bf16 (residual)
    const int t = threadIdx.x;
    const int row0 = blockIdx.x * 64;
    const int wv = t >> 6, l = t & 63;
    const int c = l & 15, g = l >> 4;

    // ---- stage y1 rows, split hi+lo ----
    const float* src = y1g + (size_t)row0 * 128;
    #pragma unroll
    for (int i = 0; i < 8; i++) {
        const int o = t * 4 + i * 1024;
        const float4 v = *(const float4*)(src + o);
        const int r = o >> 7, cc = o & 127;
        ushort4 hs, ls;
        const u16 h0 = f2u(v.x), h1 = f2u(v.y), h2 = f2u(v.z), h3 = f2u(v.w);
        hs.x = h0; hs.y = h1; hs.z = h2; hs.w = h3;
        ls.x = f2u(v.x - u2f(h0)); ls.y = f2u(v.y - u2f(h1));
        ls.z = f2u(v.z - u2f(h2)); ls.w = f2u(v.w - u2f(h3));
        *(ushort4*)&AH[swz(r, cc)] = hs;
        *(ushort4*)&AL[swz(r, cc)] = ls;
    }
    __syncthreads();

    // ---- MFMA: rows [wv*16, +16) x all 128 cols ----
    short8 aH[4], aL[4];
    #pragma unroll
    for (int kc = 0; kc < 4; kc++) {
        aH[kc] = *(const short8*)&AH[swz(wv * 16 + c, kc * 32 + g * 8)];
        aL[kc] = *(const short8*)&AL[swz(wv * 16 + c, kc * 32 + g * 8)];
    }
    #pragma unroll
    for (int nt = 0; nt < 8; nt++) {
        const float bz = bvl[nt * 16 + c];
        f32x4 acc = { bz, bz, bz, bz };
        #pragma unroll
        for (int kc = 0; kc < 4; kc++) {
            const short8 bf = *(const short8*)(wvlF + ((nt * 4 + kc) * 64 + l) * 8);
            acc = MFMA(aH[kc], bf, acc, 0, 0, 0);
            acc = MFMA(aL[kc], bf, acc, 0, 0, 0);
        }
        #pragma unroll
        for (int r = 0; r < 4; r++)
            emb[(size_t)(row0 + wv * 16 + g * 4 + r) * 128 + nt * 16 + c] = f2u(acc[r]);
    }
}

// ============ Kernel A (mid-ws): exact R5 kernel (emb tail in-wave) ============
__global__ __launch_bounds__(256) void rwa_walk_wave(
    const float* __restrict__ timef, const float* __restrict__ ppf,
    const float* __restrict__ pnf,  const float* __restrict__ wgt,
    const int*  __restrict__ sgn,
    const u16* __restrict__ fragQ, const float* __restrict__ vk,
    const u16* __restrict__ wvlT, const float* __restrict__ bvl,
    u16* __restrict__ emb)
{
    __shared__ __align__(16) u16 XS[4][4096];
    const int t  = threadIdx.x;
    const int wv = t >> 6, l = t & 63;
    const int wid  = blockIdx.x * 4 + wv;
    const int walk = wid >> 1, side = wid & 1;
    const int c = l & 15, g = l >> 4;
    u16* const xw = &XS[wv][0];

    const int row = l & 31, h = l >> 5;
    const int tok = walk * 32 + row;
    const float* tfp = timef + tok * 108;
    const float* pb = ((sgn[tok] > 0) == (side == 0)) ? (ppf + tok * 19) : (pnf + tok * 19);
    float ra = 0.f;
    #pragma unroll
    for (int ch = 0; ch < 8; ch++) {
        float tmp[8];
        #pragma unroll
        for (int j = 0; j < 8; j++) {
            const int hf = ch * 8 + j;
            float val;
            if (h == 0) val = (hf < 19) ? pb[hf] : tfp[hf - 19];
            else        val = (hf < 63) ? tfp[45 + hf] : wgt[tok];
            tmp[j] = val;
        }
        const float4 k4a = *(const float4*)(vk + h * 64 + ch * 8);
        const float4 k4b = *(const float4*)(vk + h * 64 + ch * 8 + 4);
        ra += tmp[0] * k4a.x + tmp[1] * k4a.y + tmp[2] * k4a.z + tmp[3] * k4a.w
            + tmp[4] * k4b.x + tmp[5] * k4b.y + tmp[6] * k4b.z + tmp[7] * k4b.w;
        short8 pk;
        #pragma unroll
        for (int j = 0; j < 8; j++) pk[j] = (short)f2u(tmp[j]);
        *(short8*)&xw[swz(row, h * 64 + ch * 8)] = pk;
    }
    ra += __shfl_xor(ra, 32);
    ra *= SCALE;

    short8 af[2][4];
    #pragma unroll
    for (int it = 0; it < 2; it++)
        #pragma unroll
        for (int kc = 0; kc < 4; kc++)
            af[it][kc] = *(const short8*)&xw[swz(it * 16 + c, kc * 32 + g * 8)];

    #pragma unroll
    for (int nt = 0; nt < 8; nt++) {
        f32x4 a0 = {0.f, 0.f, 0.f, 0.f}, a1 = {0.f, 0.f, 0.f, 0.f};
        #pragma unroll
        for (int kc = 0; kc < 4; kc++) {
            const short8 bf = *(const short8*)(fragQ + ((nt * 4 + kc) * 64 + l) * 8);
            a0 = MFMA(af[0][kc], bf, a0, 0, 0, 0);
            a1 = MFMA(af[1][kc], bf, a1, 0, 0, 0);
        }
        #pragma unroll
        for (int r = 0; r < 4; r++) {
            xw[swz(g * 4 + r,      nt * 16 + c)] = f2u(a0[r]);
            xw[swz(16 + g * 4 + r, nt * 16 + c)] = f2u(a1[r]);
        }
    }

    f32x4 sa[2][2];
    #pragma unroll
    for (int it = 0; it < 2; it++) {
        short8 tg[4];
        #pragma unroll
        for (int kc = 0; kc < 4; kc++)
            tg[kc] = *(const short8*)&xw[swz(it * 16 + c, kc * 32 + g * 8)];
        #pragma unroll
        for (int jt = 0; jt < 2; jt++) {
            f32x4 acc = {0.f, 0.f, 0.f, 0.f};
            #pragma unroll
            for (int kc = 0; kc < 4; kc++)
                acc = MFMA(tg[kc], af[jt][kc], acc, 0, 0, 0);
            sa[it][jt] = acc;
        }
    }
    const float ra0 = __shfl(ra, c);
    const float ra1 = __shfl(ra, 16 + c);
    float cs0 = 0.f, cs1 = 0.f;
    #pragma unroll
    for (int it = 0; it < 2; it++)
    #pragma unroll
    for (int r = 0; r < 4; r++) {
        const float s0v = sa[it][0][r] + ra0;
        const float s1v = sa[it][1][r] + ra1;
        float m0 = fmaxf(s0v, s1v);
        m0 = fmaxf(m0, __shfl_xor(m0, 1));
        m0 = fmaxf(m0, __shfl_xor(m0, 2));
        m0 = fmaxf(m0, __shfl_xor(m0, 4));
        m0 = fmaxf(m0, __shfl_xor(m0, 8));
        const float p0 = __expf(s0v - m0);
        const float p1 = __expf(s1v - m0);
        float sm = p0 + p1;
        sm += __shfl_xor(sm, 1); sm += __shfl_xor(sm, 2);
        sm += __shfl_xor(sm, 4); sm += __shfl_xor(sm, 8);
        const float inv = 1.f / sm;
        cs0 += p0 * inv; cs1 += p1 * inv;
    }
    cs0 += __shfl_xor(cs0, 16); cs0 += __shfl_xor(cs0, 32);
    cs1 += __shfl_xor(cs1, 16); cs1 += __shfl_xor(cs1, 32);

    #pragma unroll
    for (int it = 0; it < 2; it++)
        #pragma unroll
        for (int kc = 0; kc < 4; kc++)
            *(short8*)&xw[swz(it * 16 + c, kc * 32 + g * 8)] = af[it][kc];

    float y0 = 0.f, y1v = 0.f;
    #pragma unroll
    for (int j = 0; j < 16; j++) {
        const float cj = rdlane(cs0, j);
        const u32 xv = *(const u32*)&xw[swz(j, 2 * l)];
        y0 += cj * lo16(xv); y1v += cj * hi16(xv);
    }
    #pragma unroll
    for (int j = 0; j < 16; j++) {
        const float cj = rdlane(cs1, j);
        const u32 xv = *(const u32*)&xw[swz(16 + j, 2 * l)];
        y0 += cj * lo16(xv); y1v += cj * hi16(xv);
    }

    float* const yb = (float*)xw;
    *(float2*)&yb[2 * l] = make_float2(y0, y1v);

    const float2 bb = *(const float2*)&bvl[2 * l];
    float e0 = bb.x, e1 = bb.y;
    const u32* wrow = (const u32*)wvlT + l * 128;
    const float4* yf = (const float4*)yb;
    #pragma unroll 8
    for (int eq = 0; eq < 32; eq++) {
        const u32x4 w4 = *(const u32x4*)(wrow + 4 * eq);
        const float4 y4 = yf[eq];
        e0 += y4.x * lo16(w4[0]) + y4.y * lo16(w4[1]) + y4.z * lo16(w4[2]) + y4.w * lo16(w4[3]);
        e1 += y4.x * hi16(w4[0]) + y4.y * hi16(w4[1]) + y4.z * hi16(w4[2]) + y4.w * hi16(w4[3]);
    }
    const u32 pk = (u32)f2u(e0) | ((u32)f2u(e1) << 16);
    ((u32*)emb)[(side * 8192 + walk) * 64 + l] = pk;
}

// ============ Kernel B: level-2, 4-wave cooperative block per (side,b) ============
__global__ __launch_bounds__(256) void rwa_path_wave(
    const u16* __restrict__ embg, const u16* __restrict__ fragP,
    const float* __restrict__ vp, const float* __restrict__ Wvp,
    const float* __restrict__ bvp, float* __restrict__ out)
{
    __shared__ __align__(16) u16 ES[8192];     // [64][128] swizzled emb
    __shared__ __align__(16) u16 TS[8192];     // [64][128] swizzled t2
    __shared__ float raS[64];
    __shared__ float csP[4][64];
    __shared__ float y2S[4][128];
    __shared__ float y2F[128];
    __shared__ float outS[4][128];
    const int t  = threadIdx.x;
    const int sb = blockIdx.x;                 // side*128 + b
    const int wv = t >> 6, l = t & 63;
    const int c = l & 15, g = l >> 4;

    {
        const int row = t >> 2, q = t & 3;
        const u16* src = embg + (size_t)sb * 8192 + row * 128 + q * 32;
        const float* vq = vp + q * 32;
        float p = 0.f;
        #pragma unroll
        for (int i = 0; i < 4; i++) {
            const short8 ev = *(const short8*)(src + 8 * i);
            #pragma unroll
            for (int j = 0; j < 8; j++) p += u2f((u16)ev[j]) * vq[8 * i + j];
            *(short8*)&ES[swz(row, q * 32 + 8 * i)] = ev;
        }
        p += __shfl_xor(p, 1);
        p += __shfl_xor(p, 2);
        if (q == 0) raS[row] = p * SCALE;
    }
    __syncthreads();

    {
        const int it = wv;
        short8 afr[4];
        #pragma unroll
        for (int kc = 0; kc < 4; kc++)
            afr[kc] = *(const short8*)&ES[swz(it * 16 + c, kc * 32 + g * 8)];
        #pragma unroll
        for (int nt = 0; nt < 8; nt++) {
            f32x4 acc = {0.f, 0.f, 0.f, 0.f};
            #pragma unroll
            for (int kc = 0; kc < 4; kc++) {
                const short8 bf = *(const short8*)(fragP + ((nt * 4 + kc) * 64 + l) * 8);
                acc = MFMA(afr[kc], bf, acc, 0, 0, 0);
            }
            #pragma unroll
            for (int r = 0; r < 4; r++)
                TS[swz(it * 16 + g * 4 + r, nt * 16 + c)] = f2u(acc[r]);
        }
    }
    __syncthreads();

    {
        const int it = wv;
        short8 tg[4];
        #pragma unroll
        for (int kc = 0; kc < 4; kc++)
            tg[kc] = *(const short8*)&TS[swz(it * 16 + c, kc * 32 + g * 8)];
        f32x4 sa[4];
        float raj[4];
        #pragma unroll
        for (int jt = 0; jt < 4; jt++) {
            f32x4 acc = {0.f, 0.f, 0.f, 0.f};
            #pragma unroll
            for (int kc = 0; kc < 4; kc++) {
                const short8 be = *(const short8*)&ES[swz(jt * 16 + c, kc * 32 + g * 8)];
                acc = MFMA(tg[kc], be, acc, 0, 0, 0);
            }
            sa[jt] = acc;
            raj[jt] = raS[jt * 16 + c];
        }
        float cs[4] = {0.f, 0.f, 0.f, 0.f};
        #pragma unroll
        for (int r = 0; r < 4; r++) {
            float p0 = sa[0][r] + raj[0], p1 = sa[1][r] + raj[1];
            float p2 = sa[2][r] + raj[2], p3 = sa[3][r] + raj[3];
            float m0 = fmaxf(fmaxf(p0, p1), fmaxf(p2, p3));
            m0 = fmaxf(m0, __shfl_xor(m0, 1));
            m0 = fmaxf(m0, __shfl_xor(m0, 2));
            m0 = fmaxf(m0, __shfl_xor(m0, 4));
            m0 = fmaxf(m0, __shfl_xor(m0, 8));
            p0 = __expf(p0 - m0); p1 = __expf(p1 - m0);
            p2 = __expf(p2 - m0); p3 = __expf(p3 - m0);
            float sm = p0 + p1 + p2 + p3;
            sm += __shfl_xor(sm, 1); sm += __shfl_xor(sm, 2);
            sm += __shfl_xor(sm, 4); sm += __shfl_xor(sm, 8);
            const float inv = 1.f / sm;
            cs[0] += p0 * inv; cs[1] += p1 * inv; cs[2] += p2 * inv; cs[3] += p3 * inv;
        }
        #pragma unroll
        for (int jt = 0; jt < 4; jt++) {
            cs[jt] += __shfl_xor(cs[jt], 16);
            cs[jt] += __shfl_xor(cs[jt], 32);
        }
        if (g == 0) {
            #pragma unroll
            for (int jt = 0; jt < 4; jt++) csP[wv][jt * 16 + c] = cs[jt];
        }
    }
    __syncthreads();

    {
        float y0 = 0.f, y1v = 0.f;
        #pragma unroll
        for (int jj = 0; jj < 16; jj++) {
            const int j = wv * 16 + jj;
            const float cj = csP[0][j] + csP[1][j] + csP[2][j] + csP[3][j];
            const u32 xv = *(const u32*)&ES[swz(j, 2 * l)];
            y0 += cj * lo16(xv); y1v += cj * hi16(xv);
        }
        y2S[wv][2 * l] = y0; y2S[wv][2 * l + 1] = y1v;
    }
    __syncthreads();
    if (t < 128) y2F[t] = y2S[0][t] + y2S[1][t] + y2S[2][t] + y2S[3][t];
    __syncthreads();

    {
        float o0 = 0.f, o1 = 0.f;
        const float2* w2p = (const float2*)Wvp;
        #pragma unroll
        for (int k = 0; k < 32; k++) {
            const int e = wv * 32 + k;
            const float ye = y2F[e];
            const float2 w2 = w2p[e * 64 + l];
            o0 += ye * w2.x; o1 += ye * w2.y;
        }
        outS[wv][2 * l] = o0; outS[wv][2 * l + 1] = o1;
    }
    __syncthreads();
    if (t < 128)
        out[sb * 128 + t] = 64.f * bvp[t] + outS[0][t] + outS[1][t] + outS[2][t] + outS[3][t];
}

// ============ Fallback: proven fused kernel (used only if ws too small) ============
__global__ __launch_bounds__(256) void rwa_fused_fb(
    const float* timef, const float* ppf, const float* pnf, const float* wgt,
    const int* __restrict__ sgn,
    const float* Wq, const float* bq, const float* Wk, const float* bk,
    const float* Wv, const float* bv, const float* Wl, const float* bl,
    const float* Wqp, const float* bqp, const float* Wkp, const float* bkp,
    const float* Wvp, const float* bvp, float* out)
{
    extern __shared__ __align__(16) char S[];
    char* const U = S;
    float (* const sc)[33]     = (float(*)[33])(S + 41088);
    u16   (* const embs)[128]  = (u16  (*)[128])(S + 45312);
    float* const csumA         = (float*)(S + 61696);
    float* const y1            = (float*)(S + 61824);
    float* const e1            = (float*)(S + 62336);
    u16   (* const xs)[128]   = (u16  (*)[128])U;
    float (* const qs)[128]   = (float(*)[128])(U + 8192);
    float (* const ks)[129]   = (float(*)[129])(U + 8192 + 16384);
    float (* const k2s)[129]  = (float(*)[129])U;
    float (* const qrow)[128] = (float(*)[128])(U + 33024);
    float (* const csum2)[64] = (float(*)[64])(U + 35072);

    const int t    = threadIdx.x;
    const int side = blockIdx.x >> 7;
    const int b    = blockIdx.x & 127;
    const int wv_  = t >> 6;
    const int lane = t & 63;

    for (int w = 0; w < 64; ++w) {
        const int tokb = (b * 64 + w) * 32;
        for (int o = t; o < 32 * 128; o += 256) {
            const int l = o >> 7, f = o & 127;
            const int tok = tokb + l;
            float v;
            if (f < 19) {
                const bool takeP = (sgn[tok] > 0) == (side == 0);
                v = takeP ? ppf[tok * 19 + f] : pnf[tok * 19 + f];
            } else if (f < 127) v = timef[tok * 108 + (f - 19)];
            else v = wgt[tok];
            xs[l][f] = f2u(v);
        }
        __syncthreads();
        {
            const int d = t & 127, l0 = t >> 7;
            float aq[16], ak[16];
            const float bqv = bq[d], bkv = bk[d];
            #pragma unroll
            for (int i = 0; i < 16; i++) { aq[i] = bqv; ak[i] = bkv; }
            for (int e = 0; e < 128; e += 4) {
                float xv[16][4];
                #pragma unroll
                for (int i = 0; i < 16; i++) {
                    const ushort4 u = *(const ushort4*)&xs[l0 + 2 * i][e];
                    xv[i][0] = u2f(u.x); xv[i][1] = u2f(u.y);
                    xv[i][2] = u2f(u.z); xv[i][3] = u2f(u.w);
                }
                #pragma unroll
                for (int r = 0; r < 4; r++) {
                    const float wq = Wq[(e + r) * 128 + d];
                    const float wk = Wk[(e + r) * 128 + d];
                    #pragma unroll
                    for (int i = 0; i < 16; i++) {
                        aq[i] += xv[i][r] * wq; ak[i] += xv[i][r] * wk;
                    }
                }
            }
            #pragma unroll
            for (int i = 0; i < 16; i++) { const int l = l0 + 2 * i; qs[l][d] = aq[i]; ks[l][d] = ak[i]; }
        }
        __syncthreads();
        for (int o = t; o < 1024; o += 256) {
            const int i = o >> 5, j = o & 31;
            float a0 = 0, a1 = 0, a2 = 0, a3 = 0;
            for (int e = 0; e < 128; e += 4) {
                const float4 q4 = *(const float4*)&qs[i][e];
                a0 += q4.x * ks[j][e];     a1 += q4.y * ks[j][e + 1];
                a2 += q4.z * ks[j][e + 2]; a3 += q4.w * ks[j][e + 3];
            }
            sc[i][j] = (a0 + a1 + a2 + a3) * SCALE;
        }
        __syncthreads();
        if (t < 32) {
            float m = -1e30f;
            for (int j = 0; j < 32; j++) m = fmaxf(m, sc[t][j]);
            float s = 0.f;
            for (int j = 0; j < 32; j++) { const float e0 = __expf(sc[t][j] - m); sc[t][j] = e0; s += e0; }
            const float inv = 1.f / s;
            for (int j = 0; j < 32; j++) sc[t][j] *= inv;
        }
        __syncthreads();
        if (t < 32) { float s = 0.f; for (int i = 0; i < 32; i++) s += sc[i][t]; csumA[t] = s; }
        __syncthreads();
        if (t < 128) { float a = 0.f; for (int j = 0; j < 32; j++) a += csumA[j] * u2f(xs[j][t]); y1[t] = a; }
        __syncthreads();
        if (t < 128) {
            float a = 32.f * bv[t];
            for (int e = 0; e < 128; e++) a += y1[e] * Wv[e * 128 + t];
            e1[t] = a;
        }
        __syncthreads();
        if (t < 128) {
            float a = bl[t];
            for (int f = 0; f < 128; f++) a += e1[f] * Wl[f * 128 + t];
            embs[w][t] = f2u(a);
        }
        __syncthreads();
    }
    {
        const int d = t & 127, j0 = t >> 7;
        float ak2[32];
        const float bkv = bkp[d];
        #pragma unroll
        for (int i = 0; i < 32; i++) ak2[i] = bkv;
        for (int e = 0; e < 128; e++) {
            const float wk = Wkp[e * 128 + d];
            #pragma unroll
            for (int i = 0; i < 32; i++) ak2[i] += u2f(embs[j0 + 2 * i][e]) * wk;
        }
        #pragma unroll
        for (int i = 0; i < 32; i++) k2s[j0 + 2 * i][d] = ak2[i];
    }
    csum2[wv_][lane] = 0.f;
    __syncthreads();
    for (int i0 = 0; i0 < 64; i0 += 4) {
        const int r = i0 + wv_;
        {
            float a0 = bqp[lane], a1 = bqp[lane + 64];
            for (int e = 0; e < 128; e++) {
                const float xv = u2f(embs[r][e]);
                a0 += xv * Wqp[e * 128 + lane];
                a1 += xv * Wqp[e * 128 + lane + 64];
            }
            qrow[wv_][lane] = a0; qrow[wv_][lane + 64] = a1;
        }
        {
            const int j = lane;
            float s = 0.f;
            for (int e = 0; e < 128; e += 4) {
                const float4 q4 = *(const float4*)&qrow[wv_][e];
                s += q4.x * k2s[j][e] + q4.y * k2s[j][e + 1] + q4.z * k2s[j][e + 2] + q4.w * k2s[j][e + 3];
            }
            s *= SCALE;
            float m = s;
            #pragma unroll
            for (int off = 32; off; off >>= 1) m = fmaxf(m, __shfl_xor(m, off));
            const float e0 = __expf(s - m);
            float sum = e0;
            #pragma unroll
            for (int off = 32; off; off >>= 1) sum += __shfl_xor(sum, off);
            csum2[wv_][j] += e0 / sum;
        }
        __syncthreads();
    }
    if (t < 64) csum2[0][t] = csum2[0][t] + csum2[1][t] + csum2[2][t] + csum2[3][t];
    __syncthreads();
    if (t < 128) { float a = 0.f; for (int j = 0; j < 64; j++) a += csum2[0][j] * u2f(embs[j][t]); y1[t] = a; }
    __syncthreads();
    if (t < 128) {
        float a = 64.f * bvp[t];
        for (int e = 0; e < 128; e++) a += y1[e] * Wvp[e * 128 + t];
        out[blockIdx.x * 128 + t] = a;
    }
}

extern "C" void kernel_launch(void* const* d_in, const int* in_sizes, int n_in,
                              void* d_out, int out_size, void* d_ws, size_t ws_size,
                              hipStream_t stream) {
    const float* timef = (const float*)d_in[0];
    const float* ppf   = (const float*)d_in[1];
    const float* pnf   = (const float*)d_in[2];
    const float* wgt   = (const float*)d_in[3];
    const int*   sgn   = (const int*)  d_in[4];
    const float* Wq  = (const float*)d_in[5];  const float* bq  = (const float*)d_in[6];
    const float* Wk  = (const float*)d_in[7];  const float* bk  = (const float*)d_in[8];
    const float* Wv  = (const float*)d_in[9];  const float* bv  = (const float*)d_in[10];
    const float* Wl  = (const float*)d_in[11]; const float* bl  = (const float*)d_in[12];
    const float* Wqp = (const float*)d_in[13]; const float* bqp = (const float*)d_in[14];
    const float* Wkp = (const float*)d_in[15]; const float* bkp = (const float*)d_in[16];
    const float* Wvp = (const float*)d_in[17]; const float* bvp = (const float*)d_in[18];
    float* out = (float*)d_out;
    (void)in_sizes; (void)n_in; (void)out_size;

    // ws layout: frag 64KB @0 | vv 1KB @65536 | wvlT 32KB @66560 | wvlF 32KB @99328 |
    //            bvl 512B @132096 | emb 4MB @132608 | y1 f32 8MB @4326912
    u16*   frag = (u16*)d_ws;
    float* vv   = (float*)((char*)d_ws + 65536);
    u16*   wvlT = (u16*)((char*)d_ws + 66560);
    u16*   wvlF = (u16*)((char*)d_ws + 99328);
    float* bvl  = (float*)((char*)d_ws + 132096);
    u16*   emb  = (u16*)((char*)d_ws + 132608);
    float* y1g  = (float*)((char*)d_ws + 4326912);
    const size_t need_mid = 132608 + (size_t)2 * 8192 * 128 * sizeof(u16);        // ~4.33MB
    const size_t need_big = 4326912 + (size_t)16384 * 128 * sizeof(float);        // ~12.7MB

    if (ws_size >= need_big) {
        hipLaunchKernelGGL(prep_aq,  dim3(66),  dim3(256), 0, stream,
                           Wq, Wk, bq, Wqp, Wkp, bqp, frag, vv);
        hipLaunchKernelGGL(prep_wvl, dim3(129), dim3(128), 0, stream,
                           Wv, bv, Wl, bl, wvlT, wvlF, bvl);
        hipLaunchKernelGGL(rwa_walk_y1, dim3(4096), dim3(256), 0, stream,
                           timef, ppf, pnf, wgt, sgn, frag, vv, y1g);
        hipLaunchKernelGGL(rwa_emb_gemm, dim3(256), dim3(256), 0, stream,
                           y1g, wvlF, bvl, emb);
        hipLaunchKernelGGL(rwa_path_wave, dim3(256), dim3(256), 0, stream,
                           emb, frag + 16384, vv + 128, Wvp, bvp, out);
    } else if (ws_size >= need_mid) {
        hipLaunchKernelGGL(prep_aq,  dim3(66),  dim3(256), 0, stream,
                           Wq, Wk, bq, Wqp, Wkp, bqp, frag, vv);
        hipLaunchKernelGGL(prep_wvl, dim3(129), dim3(128), 0, stream,
                           Wv, bv, Wl, bl, wvlT, wvlF, bvl);
        hipLaunchKernelGGL(rwa_walk_wave, dim3(4096), dim3(256), 0, stream,
                           timef, ppf, pnf, wgt, sgn, frag, vv, wvlT, bvl, emb);
        hipLaunchKernelGGL(rwa_path_wave, dim3(256), dim3(256), 0, stream,
                           emb, frag + 16384, vv + 128, Wvp, bvp, out);
    } else {
        hipLaunchKernelGGL(rwa_fused_fb, dim3(256), dim3(256), 62848, stream,
                           timef, ppf, pnf, wgt, sgn, Wq, bq, Wk, bk, Wv, bv, Wl, bl,
                           Wqp, bqp, Wkp, bkp, Wvp, bvp, out);
    }
}